// Round 11
// baseline (406.616 us; speedup 1.0000x reference)
//
#include <hip/hip_runtime.h>
#include <hip/hip_bf16.h>
#include <stdint.h>

typedef unsigned short u16;
typedef __attribute__((ext_vector_type(8))) short short8;   // 8 bf16 (4 VGPRs)
typedef __attribute__((ext_vector_type(4))) float f32x4;
typedef __attribute__((ext_vector_type(2))) float f32x2;

union B8 { short8 v; u16 u[8]; };
union U4 { unsigned long long q; u16 u[4]; };

__device__ __forceinline__ float b2f(u16 b) {
  union { unsigned int i; float f; } x; x.i = ((unsigned int)b) << 16; return x.f;
}
__device__ __forceinline__ u16 f2b(float f) {
  __hip_bfloat16 h = __float2bfloat16(f);
  return *reinterpret_cast<u16*>(&h);
}

// async global->LDS, 16B/lane, LDS dest = wave-uniform base + lane*16 [m97]
#define GLOAD_LDS16(gp, lp)                                                  \
  __builtin_amdgcn_global_load_lds(                                          \
      (const __attribute__((address_space(1))) unsigned int*)(gp),           \
      (__attribute__((address_space(3))) unsigned int*)(lp), 16, 0, 0)

// ------- merged convert fp32 -> bf16 for x / down / up (each 4096 blks) ----
__global__ __launch_bounds__(256) void cvt3(
    const float* __restrict__ s0, const float* __restrict__ s1,
    const float* __restrict__ s2,
    u16* __restrict__ d0, u16* __restrict__ d1, u16* __restrict__ d2) {
  int grp = blockIdx.x >> 12, blk = blockIdx.x & 4095;
  const float* src = grp == 0 ? s0 : (grp == 1 ? s1 : s2);
  u16*        dst = grp == 0 ? d0 : (grp == 1 ? d1 : d2);
  size_t i = ((size_t)blk * 256 + threadIdx.x) * 4;
  f32x4 v = *(const f32x4*)(src + i);
  U4 o;
#pragma unroll
  for (int j = 0; j < 4; ++j) o.u[j] = f2b(v[j]);
  *(unsigned long long*)(dst + i) = o.q;
}

// ---------------- convert + transpose: fp32 W[K][N] -> bf16 WT[N][K] -------
// z-merged: blockIdx.z selects (W0,WT0) or (W1,WT1).
__global__ __launch_bounds__(256) void convt_w(
    const float* __restrict__ W0, u16* __restrict__ WT0,
    const float* __restrict__ W1, u16* __restrict__ WT1,
    int K, int N) {
  const float* W = blockIdx.z ? W1 : W0;
  u16* WT = blockIdx.z ? WT1 : WT0;
  int k  = blockIdx.x * 64 + (threadIdx.x & 63);
  int n8 = blockIdx.y * 32 + (threadIdx.x >> 6) * 8;
  const float* p = W + (size_t)k * N + n8;
  f32x4 a = *(const f32x4*)(p);
  f32x4 b = *(const f32x4*)(p + 4);
#pragma unroll
  for (int j = 0; j < 4; ++j) WT[(size_t)(n8 + j) * K + k] = f2b(a[j]);
#pragma unroll
  for (int j = 0; j < 4; ++j) WT[(size_t)(n8 + 4 + j) * K + k] = f2b(b[j]);
}

// ------ keys transpose: fp32 [H=4][K=64][P=2][N=64] -> [H][P][N][K] --------
__global__ __launch_bounds__(256) void convt_keys(const float* __restrict__ keys,
                                                  float* __restrict__ keysT) {
  int h = blockIdx.x, p = blockIdx.y;
  int k  = threadIdx.x >> 2;            // 0..63
  int n0 = (threadIdx.x & 3) * 16;      // 0,16,32,48
  const float* src = keys + ((size_t)(h * 64 + k) * 2 + p) * 64 + n0;
  float* dst = keysT + (((size_t)h * 2 + p) * 64) * 64 + k;
#pragma unroll
  for (int c = 0; c < 16; ++c)
    dst[(size_t)(n0 + c) * 64] = src[c];
}

// ------- small GEMM (q-projection), BK=64 + swizzle [r9-proven] ------------
__global__ __launch_bounds__(256) void gemm_bf16(
    const u16* __restrict__ A, const u16* __restrict__ BT,
    const float* __restrict__ bias,
    u16* __restrict__ Cb, int M, int N, int K)
{
  __shared__ __attribute__((aligned(16))) u16 As[128 * 64];
  __shared__ __attribute__((aligned(16))) u16 Bs[128 * 64];
  int tid = threadIdx.x;
  int m0 = blockIdx.y * 128, n0 = blockIdx.x * 128;
  int wave = tid >> 6, lane = tid & 63;
  int wm = (wave >> 1) * 64, wn = (wave & 1) * 64;
  int quad = lane >> 4, r16 = lane & 15;
  int s7 = r16 & 7;

  int srow = lane >> 3;
  int scol = ((lane & 7) ^ srow) * 8;
  const u16* aG = A  + (size_t)(m0 + wave * 32 + srow) * K + scol;
  const u16* bG = BT + (size_t)(n0 + wave * 32 + srow) * K + scol;

  f32x4 acc[4][4] = {};

  for (int k0 = 0; k0 < K; k0 += 64) {
#pragma unroll
    for (int idx = 0; idx < 4; ++idx) {
      size_t go = (size_t)idx * 8 * K + k0;
      int lo = wave * 2048 + idx * 512;
      GLOAD_LDS16(aG + go, As + lo);
      GLOAD_LDS16(bG + go, Bs + lo);
    }
    __syncthreads();
#pragma unroll
    for (int kk = 0; kk < 2; ++kk) {
      short8 af[4], bfr[4];
#pragma unroll
      for (int i = 0; i < 4; ++i)
        af[i] = *(const short8*)(&As[(wm + i * 16 + r16) * 64
                                     + (((kk << 2) + quad) ^ s7) * 8]);
#pragma unroll
      for (int j = 0; j < 4; ++j)
        bfr[j] = *(const short8*)(&Bs[(wn + j * 16 + r16) * 64
                                      + (((kk << 2) + quad) ^ s7) * 8]);
#pragma unroll
      for (int i = 0; i < 4; ++i)
#pragma unroll
        for (int j = 0; j < 4; ++j)
          acc[i][j] = __builtin_amdgcn_mfma_f32_16x16x32_bf16(af[i], bfr[j], acc[i][j], 0, 0, 0);
    }
    __syncthreads();
  }

  // C/D layout: col = lane&15, row = quad*4 + reg   [m89-verified]
#pragma unroll
  for (int i = 0; i < 4; ++i) {
    int row = m0 + wm + i * 16 + quad * 4;
#pragma unroll
    for (int j = 0; j < 4; ++j) {
      int col = n0 + wn + j * 16 + r16;
      float bv = bias ? bias[col] : 0.f;
#pragma unroll
      for (int r = 0; r < 4; ++r) {
        float v = acc[i][j][r] + bv;
        Cb[(size_t)(row + r) * N + col] = f2b(v);
      }
    }
  }
}

// ------- fused gate+up GEMM, 128x256 tile, BK=128, 8 waves -----------------
// r11: drain model harder. K-steps 16 -> 8, 128 MFMA/wave per drain pair.
// LDS = A 32K + G 64K + U 64K = 160 KB (1 blk/CU; wave-parallelism unchanged:
// 8 waves/CU = 2/SIMD, same as r9's 2 blk x 4 waves). Swizzle: 16B-block
// ^= (row&3)<<2 (gload covers 4 rows -> idx-invariant; banks uniform since
// bank depends on block mod 8 and the XOR keeps all 16 blocks distinct).
__global__ __launch_bounds__(512, 2) void gemm_gu(
    const u16* __restrict__ A, const u16* __restrict__ BgT,
    const u16* __restrict__ BuT,
    const float* __restrict__ bg, const float* __restrict__ bu,
    u16* __restrict__ H, int M, int N, int K)
{
  __shared__ __attribute__((aligned(16))) u16 As[128 * 128];   // 32 KB
  __shared__ __attribute__((aligned(16))) u16 Gs[256 * 128];   // 64 KB
  __shared__ __attribute__((aligned(16))) u16 Us[256 * 128];   // 64 KB
  int tid = threadIdx.x;
  int m0 = blockIdx.y * 128, n0 = blockIdx.x * 256;
  int wid = tid >> 6, lane = tid & 63;
  int wm2 = (wid >> 2) * 64, wn2 = (wid & 3) * 64;   // 2M x 4N waves
  int quad = lane >> 4, r16 = lane & 15;
  int r4 = lane >> 4;                                // stage row-in-4
  int cblk = ((lane & 15) ^ (r4 << 2)) * 8;          // swizzled src col (u16)

  const u16* aG = A   + (size_t)(m0 + wid * 16 + r4) * K + cblk;
  const u16* gG = BgT + (size_t)(n0 + wid * 32 + r4) * K + cblk;
  const u16* uG = BuT + (size_t)(n0 + wid * 32 + r4) * K + cblk;

  f32x4 ag[4][4] = {}, au[4][4] = {};

  for (int k0 = 0; k0 < K; k0 += 128) {
#pragma unroll
    for (int idx = 0; idx < 4; ++idx)
      GLOAD_LDS16(aG + (size_t)idx * 4 * K + k0, As + (wid * 16 + idx * 4) * 128);
#pragma unroll
    for (int idx = 0; idx < 8; ++idx) {
      GLOAD_LDS16(gG + (size_t)idx * 4 * K + k0, Gs + (wid * 32 + idx * 4) * 128);
      GLOAD_LDS16(uG + (size_t)idx * 4 * K + k0, Us + (wid * 32 + idx * 4) * 128);
    }
    __syncthreads();
#pragma unroll
    for (int kk = 0; kk < 4; ++kk) {
      int cb = ((((kk << 2) + quad) ^ ((r16 & 3) << 2))) * 8;
      short8 af[4], bfr[4];
#pragma unroll
      for (int i = 0; i < 4; ++i)
        af[i] = *(const short8*)(&As[(wm2 + i * 16 + r16) * 128 + cb]);
#pragma unroll
      for (int j = 0; j < 4; ++j)
        bfr[j] = *(const short8*)(&Gs[(wn2 + j * 16 + r16) * 128 + cb]);
#pragma unroll
      for (int i = 0; i < 4; ++i)
#pragma unroll
        for (int j = 0; j < 4; ++j)
          ag[i][j] = __builtin_amdgcn_mfma_f32_16x16x32_bf16(af[i], bfr[j], ag[i][j], 0, 0, 0);
#pragma unroll
      for (int j = 0; j < 4; ++j)
        bfr[j] = *(const short8*)(&Us[(wn2 + j * 16 + r16) * 128 + cb]);
#pragma unroll
      for (int i = 0; i < 4; ++i)
#pragma unroll
        for (int j = 0; j < 4; ++j)
          au[i][j] = __builtin_amdgcn_mfma_f32_16x16x32_bf16(af[i], bfr[j], au[i][j], 0, 0, 0);
    }
    __syncthreads();
  }

#pragma unroll
  for (int i = 0; i < 4; ++i) {
    int row = m0 + wm2 + i * 16 + quad * 4;
#pragma unroll
    for (int j = 0; j < 4; ++j) {
      int col = n0 + wn2 + j * 16 + r16;
      float bgv = bg[col], buv = bu[col];
#pragma unroll
      for (int r = 0; r < 4; ++r) {
        float g = ag[i][j][r] + bgv;
        float u = au[i][j][r] + buv;
        float h = (g / (1.f + __expf(-g))) * u;
        H[(size_t)(row + r) * N + col] = f2b(h);
      }
    }
  }
}

// -------- split-K down-GEMM, BK=128, XCD-aware [T1] ------------------------
// r11: occupancy is grid-capped at 2 blk/CU (512 blocks) and 64KB LDS still
// fits 2 -> drain-halving is free. K-steps 32 -> 16.
__global__ __launch_bounds__(256) void gemm_dsk(
    const u16* __restrict__ A, const u16* __restrict__ BT,
    float* __restrict__ P, int M, int N, int K, int Kslice, int mOff)
{
  __shared__ __attribute__((aligned(16))) u16 As[128 * 128];   // 32 KB
  __shared__ __attribute__((aligned(16))) u16 Bs[128 * 128];   // 32 KB
  int tid = threadIdx.x;

  int lid = blockIdx.x + blockIdx.y * gridDim.x +
            blockIdx.z * gridDim.x * gridDim.y;
  int G = gridDim.y * gridDim.z;          // (m,z) groups; n = gridDim.x = 8
  int n_blk, m_blk, z_blk;
  if ((G & 7) == 0) {
    int x = lid & 7, s = lid >> 3;        // XCD, per-XCD slot
    int gid = x * (G >> 3) + (s >> 3);    // group handled by this XCD
    n_blk = s & 7;
    m_blk = gid % gridDim.y;
    z_blk = gid / gridDim.y;
  } else {
    n_blk = blockIdx.x; m_blk = blockIdx.y; z_blk = blockIdx.z;
  }

  int m0 = m_blk * 128, n0 = n_blk * 128;
  int kb = z_blk * Kslice, ke = kb + Kslice;
  int wave = tid >> 6, lane = tid & 63;
  int wm = (wave >> 1) * 64, wn = (wave & 1) * 64;
  int quad = lane >> 4, r16 = lane & 15;
  int r4 = lane >> 4;
  int cblk = ((lane & 15) ^ (r4 << 2)) * 8;

  const u16* aG = A  + (size_t)(m0 + wave * 32 + r4) * K + cblk;
  const u16* bG = BT + (size_t)(n0 + wave * 32 + r4) * K + cblk;

  f32x4 acc[4][4] = {};

  for (int k0 = kb; k0 < ke; k0 += 128) {
#pragma unroll
    for (int idx = 0; idx < 8; ++idx) {
      size_t go = (size_t)idx * 4 * K + k0;
      int lo = (wave * 32 + idx * 4) * 128;
      GLOAD_LDS16(aG + go, As + lo);
      GLOAD_LDS16(bG + go, Bs + lo);
    }
    __syncthreads();
#pragma unroll
    for (int kk = 0; kk < 4; ++kk) {
      int cb = ((((kk << 2) + quad) ^ ((r16 & 3) << 2))) * 8;
      short8 af[4], bfr[4];
#pragma unroll
      for (int i = 0; i < 4; ++i)
        af[i] = *(const short8*)(&As[(wm + i * 16 + r16) * 128 + cb]);
#pragma unroll
      for (int j = 0; j < 4; ++j)
        bfr[j] = *(const short8*)(&Bs[(wn + j * 16 + r16) * 128 + cb]);
#pragma unroll
      for (int i = 0; i < 4; ++i)
#pragma unroll
        for (int j = 0; j < 4; ++j)
          acc[i][j] = __builtin_amdgcn_mfma_f32_16x16x32_bf16(af[i], bfr[j], acc[i][j], 0, 0, 0);
    }
    __syncthreads();
  }

  float* Pz = P + (size_t)z_blk * 4194304;   // 4096*1024 per slice
#pragma unroll
  for (int i = 0; i < 4; ++i) {
    int row = mOff + m0 + wm + i * 16 + quad * 4;
#pragma unroll
    for (int j = 0; j < 4; ++j) {
      int col = n0 + wn + j * 16 + r16;
#pragma unroll
      for (int r = 0; r < 4; ++r)
        Pz[(size_t)(row + r) * N + col] = acc[i][j][r];
    }
  }
}

// ------- fused reduce: out = sum_s P[s] + es + bd (N = 1024) ---------------
__global__ __launch_bounds__(256) void reduce_k(const float* __restrict__ part,
                                                int S,
                                                const float* __restrict__ es,
                                                const float* __restrict__ bd,
                                                float* __restrict__ out) {
  int t = blockIdx.x, c0 = threadIdx.x * 4;
  size_t off = (size_t)t * 1024 + c0;
  f32x4 a = *(const f32x4*)(es + off);
  for (int s = 0; s < S; ++s) {
    f32x4 p = *(const f32x4*)(part + (size_t)s * 4194304 + off);
#pragma unroll
    for (int c = 0; c < 4; ++c) a[c] += p[c];
  }
  f32x4 b = *(const f32x4*)(bd + c0);
  f32x4 o;
#pragma unroll
  for (int c = 0; c < 4; ++c) o[c] = a[c] + b[c];
  *(f32x4*)(out + off) = o;
}

// ======== bitonic top-8-of-64 network helpers (values spread 1/lane) =======
template<int NP>
__device__ __forceinline__ void sort8_desc(float (&v)[NP], int (&ii)[NP], int j) {
#pragma unroll
  for (int k = 2; k <= 8; k <<= 1) {
#pragma unroll
    for (int s = k >> 1; s > 0; s >>= 1) {
      bool desc  = (j & k) == 0;
      bool lower = (j & s) == 0;
#pragma unroll
      for (int p = 0; p < NP; ++p) {
        float vp = __shfl_xor(v[p], s);
        int   ip = __shfl_xor(ii[p], s);
        bool mf = (v[p] > vp) || (v[p] == vp && ii[p] < ip);
        bool keep = (desc == lower) ? mf : !mf;
        if (!keep) { v[p] = vp; ii[p] = ip; }
      }
    }
  }
}

template<int NP>
__device__ __forceinline__ void merge_top8(float (&v)[NP], int (&ii)[NP], int j) {
#pragma unroll
  for (int r = 0; r < 3; ++r) {
    int mask = (8 << r) | 7;     // partner group, mirrored position
#pragma unroll
    for (int p = 0; p < NP; ++p) {
      float vp = __shfl_xor(v[p], mask);
      int   ip = __shfl_xor(ii[p], mask);
      bool mf = (v[p] > vp) || (v[p] == vp && ii[p] < ip);
      if (!mf) { v[p] = vp; ii[p] = ip; }   // elementwise max -> bitonic seq
    }
#pragma unroll
    for (int s = 4; s > 0; s >>= 1) {       // bitonic merge, descending
      bool lower = (j & s) == 0;
#pragma unroll
      for (int p = 0; p < NP; ++p) {
        float vq = __shfl_xor(v[p], s);
        int   iq = __shfl_xor(ii[p], s);
        bool mf = (v[p] > vq) || (v[p] == vq && ii[p] < iq);
        bool keep = lower ? mf : !mf;
        if (!keep) { v[p] = vq; ii[p] = iq; }
      }
    }
  }
}

// ---------------- product-key retrieval (bitonic top-k, in-register) -------
__global__ __launch_bounds__(256) void retrieve_k(
    const u16*  __restrict__ q,      // bf16 [4096][512] = [t][p(2)][h(4)][n(64)]
    const float* __restrict__ keysT, // fp32 [4][2][64][64] = [h][p][n][k]
    int* __restrict__ idx_out,       // [4096][4][8]
    float* __restrict__ p_out)       // [4096][4][8]
{
  int t = blockIdx.x;
  int w = threadIdx.x >> 6, lane = threadIdx.x & 63;
  int j = lane & 7;

  float v[2]; int ii[2];
#pragma unroll
  for (int p = 0; p < 2; ++p) {
    const u16*   qp = q + (size_t)t * 512 + p * 256 + w * 64;   // broadcast
    const float* kp = keysT + ((size_t)(w * 2 + p) * 64) * 64 + lane;
    float s0 = 0.f, s1 = 0.f, s2 = 0.f, s3 = 0.f;   // 4-way fma ILP
#pragma unroll
    for (int n = 0; n < 64; n += 8) {
      B8 qv; qv.v = *(const short8*)(qp + n);
      s0 += b2f(qv.u[0]) * kp[(size_t)(n + 0) * 64];
      s1 += b2f(qv.u[1]) * kp[(size_t)(n + 1) * 64];
      s2 += b2f(qv.u[2]) * kp[(size_t)(n + 2) * 64];
      s3 += b2f(qv.u[3]) * kp[(size_t)(n + 3) * 64];
      s0 += b2f(qv.u[4]) * kp[(size_t)(n + 4) * 64];
      s1 += b2f(qv.u[5]) * kp[(size_t)(n + 5) * 64];
      s2 += b2f(qv.u[6]) * kp[(size_t)(n + 6) * 64];
      s3 += b2f(qv.u[7]) * kp[(size_t)(n + 7) * 64];
    }
    v[p] = (s0 + s1) + (s2 + s3); ii[p] = lane;
  }

  // phase 1: per-half top-8 of 64 (two interleaved networks)
  sort8_desc<2>(v, ii, j);
  merge_top8<2>(v, ii, j);

  // phase 2: 64 combo sums; groups pre-sorted (sy sorted), merge only
  float v2[1] = { __shfl(v[0], lane >> 3) + __shfl(v[1], lane & 7) };
  int  pos[1] = { lane };                   // combo position = tie-break key
  merge_top8<1>(v2, pos, j);

  int ex = __shfl(ii[0], pos[0] >> 3);
  int ey = __shfl(ii[1], pos[0] & 7);

  float m = __shfl(v2[0], 0);
  float e = __expf(v2[0] - m);
  float sum = e;
#pragma unroll
  for (int s = 4; s > 0; s >>= 1) sum += __shfl_xor(sum, s);

  if (lane < 8) {
    int o = (t * 4 + w) * 8 + lane;
    p_out[o]   = e / sum;
    idx_out[o] = ex * 64 + ey;
  }
}

// ---------- expert gather + weighted sum: 8 waves, 4 experts/wave ----------
__global__ __launch_bounds__(512) void expert_k(
    const u16* __restrict__ xb, const u16* __restrict__ downb,
    const u16* __restrict__ upb,
    const int* __restrict__ idx, const float* __restrict__ probs,
    float* __restrict__ es)     // [4096][1024] fp32
{
  __shared__ float acc_s[8][1024];   // 32 KB
  int t = blockIdx.x;
  int w = threadIdx.x >> 6, lane = threadIdx.x & 63;
  const size_t tb = (size_t)t * 1024;
  const int lo = lane * 8;

  B8 xv0, xv1;
  xv0.v = *(const short8*)(xb + tb + lo);
  xv1.v = *(const short8*)(xb + tb + 512 + lo);
  float xf[16];
#pragma unroll
  for (int c = 0; c < 8; ++c) { xf[c] = b2f(xv0.u[c]); xf[8 + c] = b2f(xv1.u[c]); }

  float a[16] = {};
#pragma unroll
  for (int e4 = 0; e4 < 4; ++e4) {
    int e = w * 4 + e4;
    int id = idx[t * 32 + e];
    const u16* dp = downb + (size_t)id * 1024;
    B8 d0, d1;
    d0.v = *(const short8*)(dp + lo);
    d1.v = *(const short8*)(dp + 512 + lo);
    float part = 0.f;
#pragma unroll
    for (int c = 0; c < 8; ++c)
      part += xf[c] * b2f(d0.u[c]) + xf[8 + c] * b2f(d1.u[c]);
#pragma unroll
    for (int off = 32; off; off >>= 1) part += __shfl_xor(part, off);
    float gate = (part / (1.f + __expf(-part))) * probs[t * 32 + e];
    const u16* upp = upb + (size_t)id * 1024;
    B8 u0, u1;
    u0.v = *(const short8*)(upp + lo);
    u1.v = *(const short8*)(upp + 512 + lo);
#pragma unroll
    for (int c = 0; c < 8; ++c) {
      a[c]     += gate * b2f(u0.u[c]);
      a[8 + c] += gate * b2f(u1.u[c]);
    }
  }
#pragma unroll
  for (int c = 0; c < 8; ++c) {
    acc_s[w][lo + c]       = a[c];
    acc_s[w][512 + lo + c] = a[8 + c];
  }
  __syncthreads();
  int d0i = threadIdx.x * 2;
  float o0 = 0.f, o1 = 0.f;
#pragma unroll
  for (int ww = 0; ww < 8; ++ww) {
    o0 += acc_s[ww][d0i];
    o1 += acc_s[ww][d0i + 1];
  }
  f32x2 o; o[0] = o0; o[1] = o1;
  *(f32x2*)(es + tb + d0i) = o;
}

extern "C" void kernel_launch(void* const* d_in, const int* in_sizes, int n_in,
                              void* d_out, int out_size, void* d_ws, size_t ws_size,
                              hipStream_t stream)
{
  const float* x    = (const float*)d_in[0];
  const float* Wg   = (const float*)d_in[1];
  const float* bg   = (const float*)d_in[2];
  const float* Wu   = (const float*)d_in[3];
  const float* bu   = (const float*)d_in[4];
  const float* Wd   = (const float*)d_in[5];
  const float* bd   = (const float*)d_in[6];
  const float* Wq   = (const float*)d_in[7];
  const float* keys = (const float*)d_in[8];
  const float* down = (const float*)d_in[9];
  const float* up   = (const float*)d_in[10];
  float* out = (float*)d_out;

  // --- workspace layout ---
  const size_t MB = 1048576;
  char* ws = (char*)d_ws;
  u16*   xb    = (u16*)(ws);                 // 8 MB  bf16 x [4096][1024]
  u16*   WgT   = (u16*)(ws + 8  * MB);       // 8 MB  bf16 [4096][1024]
  u16*   WuT   = (u16*)(ws + 16 * MB);       // 8 MB
  u16*   WdT   = (u16*)(ws + 24 * MB);       // 8 MB  bf16 [1024][4096]
  float* es    = (float*)(ws + 32 * MB);     // 16 MB fp32 [4096][1024]
  u16*   WqT   = (u16*)(ws + 32 * MB);       // 1 MB, aliases es head (dead first)
  u16*   qb    = (u16*)(ws + 34 * MB);       // 4 MB, aliases es (dead first)
  float* keysT = (float*)(ws + 47 * MB);     // 128 KB, aliases es tail (dead first)
  int*   idxb  = (int*)(ws + 48 * MB);       // 512 KB
  float* prb   = (float*)(ws + 48 * MB + 512 * 1024);
  u16*   downb = (u16*)(ws + 49 * MB);       // 8 MB bf16 [4096][1024]
  u16*   upb   = (u16*)(ws + 57 * MB);       // 8 MB

  // split-K partials for down-GEMM: S x 16 MB fp32 [4096][1024], then gb
  int S = 2;
  while (S > 1 && 65 * MB + (size_t)S * 16 * MB + 1 * MB > ws_size) S >>= 1;
  float* part = (float*)(ws + 65 * MB);
  size_t gboff = 65 * MB + (size_t)S * 16 * MB;
  u16*   gb    = (u16*)(ws + gboff);         // chunk_rows x 4096 bf16 (h1)

  size_t avail = ws_size > gboff ? ws_size - gboff : 0;
  int rows = 4096;                           // rows per MLP chunk
  while (rows > 128 && (size_t)rows * 4096 * 2 > avail) rows >>= 1;
  int Ksl = 4096 / S;

  // conversions (fp32 -> bf16; weights fused with transpose)
  cvt3<<<12288, 256, 0, stream>>>(x, down, up, xb, downb, upb);
  convt_w<<<dim3(16, 16),  256, 0, stream>>>(Wq, WqT, nullptr, nullptr, 1024, 512);
  convt_w<<<dim3(16, 128, 2), 256, 0, stream>>>(Wg, WgT, Wu, WuT, 1024, 4096);
  convt_w<<<dim3(64, 32),  256, 0, stream>>>(Wd, WdT, nullptr, nullptr, 4096, 1024);
  convt_keys<<<dim3(4, 2), 256, 0, stream>>>(keys, keysT);

  // retrieval chain: q = x@Wq -> topk experts -> es
  gemm_bf16<<<dim3(4, 32), 256, 0, stream>>>(xb, WqT, nullptr,
                                             qb, 4096, 512, 1024);
  retrieve_k<<<4096, 256, 0, stream>>>(qb, keysT, idxb, prb);
  expert_k<<<4096, 512, 0, stream>>>(xb, downb, upb, idxb, prb, es);

  // MLP chain: h1 = silu(x@Wg+bg)*(x@Wu+bu); P[s] = h1@Wd (split-K stores)
  for (int m0c = 0; m0c < 4096; m0c += rows) {
    int gy = rows / 128;
    gemm_gu<<<dim3(16, gy), 512, 0, stream>>>(xb + (size_t)m0c * 1024, WgT, WuT,
                                              bg, bu, gb, rows, 4096, 1024);
    gemm_dsk<<<dim3(8, gy, S), 256, 0, stream>>>(gb, WdT, part,
                                                 rows, 1024, 4096, Ksl, m0c);
  }
  // fused epilogue: out = sum_s P[s] + es + bd
  reduce_k<<<4096, 256, 0, stream>>>(part, S, es, bd, out);
}

// Round 12
// 397.987 us; speedup vs baseline: 1.0217x; 1.0217x over previous
//
#include <hip/hip_runtime.h>
#include <hip/hip_bf16.h>
#include <stdint.h>

typedef unsigned short u16;
typedef __attribute__((ext_vector_type(8))) short short8;   // 8 bf16 (4 VGPRs)
typedef __attribute__((ext_vector_type(4))) float f32x4;
typedef __attribute__((ext_vector_type(2))) float f32x2;

union B8 { short8 v; u16 u[8]; };
union U4 { unsigned long long q; u16 u[4]; };

__device__ __forceinline__ float b2f(u16 b) {
  union { unsigned int i; float f; } x; x.i = ((unsigned int)b) << 16; return x.f;
}
__device__ __forceinline__ u16 f2b(float f) {
  __hip_bfloat16 h = __float2bfloat16(f);
  return *reinterpret_cast<u16*>(&h);
}

// async global->LDS, 16B/lane, LDS dest = wave-uniform base + lane*16 [m97]
#define GLOAD_LDS16(gp, lp)                                                  \
  __builtin_amdgcn_global_load_lds(                                          \
      (const __attribute__((address_space(1))) unsigned int*)(gp),           \
      (__attribute__((address_space(3))) unsigned int*)(lp), 16, 0, 0)

// ------- merged convert fp32 -> bf16 for x / down / up (each 4096 blks) ----
__global__ __launch_bounds__(256) void cvt3(
    const float* __restrict__ s0, const float* __restrict__ s1,
    const float* __restrict__ s2,
    u16* __restrict__ d0, u16* __restrict__ d1, u16* __restrict__ d2) {
  int grp = blockIdx.x >> 12, blk = blockIdx.x & 4095;
  const float* src = grp == 0 ? s0 : (grp == 1 ? s1 : s2);
  u16*        dst = grp == 0 ? d0 : (grp == 1 ? d1 : d2);
  size_t i = ((size_t)blk * 256 + threadIdx.x) * 4;
  f32x4 v = *(const f32x4*)(src + i);
  U4 o;
#pragma unroll
  for (int j = 0; j < 4; ++j) o.u[j] = f2b(v[j]);
  *(unsigned long long*)(dst + i) = o.q;
}

// ---------------- convert + transpose: fp32 W[K][N] -> bf16 WT[N][K] -------
// z-merged: blockIdx.z selects (W0,WT0) or (W1,WT1).
__global__ __launch_bounds__(256) void convt_w(
    const float* __restrict__ W0, u16* __restrict__ WT0,
    const float* __restrict__ W1, u16* __restrict__ WT1,
    int K, int N) {
  const float* W = blockIdx.z ? W1 : W0;
  u16* WT = blockIdx.z ? WT1 : WT0;
  int k  = blockIdx.x * 64 + (threadIdx.x & 63);
  int n8 = blockIdx.y * 32 + (threadIdx.x >> 6) * 8;
  const float* p = W + (size_t)k * N + n8;
  f32x4 a = *(const f32x4*)(p);
  f32x4 b = *(const f32x4*)(p + 4);
#pragma unroll
  for (int j = 0; j < 4; ++j) WT[(size_t)(n8 + j) * K + k] = f2b(a[j]);
#pragma unroll
  for (int j = 0; j < 4; ++j) WT[(size_t)(n8 + 4 + j) * K + k] = f2b(b[j]);
}

// ------ keys transpose: fp32 [H=4][K=64][P=2][N=64] -> [H][P][N][K] --------
__global__ __launch_bounds__(256) void convt_keys(const float* __restrict__ keys,
                                                  float* __restrict__ keysT) {
  int h = blockIdx.x, p = blockIdx.y;
  int k  = threadIdx.x >> 2;            // 0..63
  int n0 = (threadIdx.x & 3) * 16;      // 0,16,32,48
  const float* src = keys + ((size_t)(h * 64 + k) * 2 + p) * 64 + n0;
  float* dst = keysT + (((size_t)h * 2 + p) * 64) * 64 + k;
#pragma unroll
  for (int c = 0; c < 16; ++c)
    dst[(size_t)(n0 + c) * 64] = src[c];
}

// ------- small GEMM (q-projection), BK=64 + swizzle [r9-proven] ------------
__global__ __launch_bounds__(256) void gemm_bf16(
    const u16* __restrict__ A, const u16* __restrict__ BT,
    const float* __restrict__ bias,
    u16* __restrict__ Cb, int M, int N, int K)
{
  __shared__ __attribute__((aligned(16))) u16 As[128 * 64];
  __shared__ __attribute__((aligned(16))) u16 Bs[128 * 64];
  int tid = threadIdx.x;
  int m0 = blockIdx.y * 128, n0 = blockIdx.x * 128;
  int wave = tid >> 6, lane = tid & 63;
  int wm = (wave >> 1) * 64, wn = (wave & 1) * 64;
  int quad = lane >> 4, r16 = lane & 15;
  int s7 = r16 & 7;

  int srow = lane >> 3;
  int scol = ((lane & 7) ^ srow) * 8;
  const u16* aG = A  + (size_t)(m0 + wave * 32 + srow) * K + scol;
  const u16* bG = BT + (size_t)(n0 + wave * 32 + srow) * K + scol;

  f32x4 acc[4][4] = {};

  for (int k0 = 0; k0 < K; k0 += 64) {
#pragma unroll
    for (int idx = 0; idx < 4; ++idx) {
      size_t go = (size_t)idx * 8 * K + k0;
      int lo = wave * 2048 + idx * 512;
      GLOAD_LDS16(aG + go, As + lo);
      GLOAD_LDS16(bG + go, Bs + lo);
    }
    __syncthreads();
#pragma unroll
    for (int kk = 0; kk < 2; ++kk) {
      short8 af[4], bfr[4];
#pragma unroll
      for (int i = 0; i < 4; ++i)
        af[i] = *(const short8*)(&As[(wm + i * 16 + r16) * 64
                                     + (((kk << 2) + quad) ^ s7) * 8]);
#pragma unroll
      for (int j = 0; j < 4; ++j)
        bfr[j] = *(const short8*)(&Bs[(wn + j * 16 + r16) * 64
                                      + (((kk << 2) + quad) ^ s7) * 8]);
#pragma unroll
      for (int i = 0; i < 4; ++i)
#pragma unroll
        for (int j = 0; j < 4; ++j)
          acc[i][j] = __builtin_amdgcn_mfma_f32_16x16x32_bf16(af[i], bfr[j], acc[i][j], 0, 0, 0);
    }
    __syncthreads();
  }

  // C/D layout: col = lane&15, row = quad*4 + reg   [m89-verified]
#pragma unroll
  for (int i = 0; i < 4; ++i) {
    int row = m0 + wm + i * 16 + quad * 4;
#pragma unroll
    for (int j = 0; j < 4; ++j) {
      int col = n0 + wn + j * 16 + r16;
      float bv = bias ? bias[col] : 0.f;
#pragma unroll
      for (int r = 0; r < 4; ++r) {
        float v = acc[i][j][r] + bv;
        Cb[(size_t)(row + r) * N + col] = f2b(v);
      }
    }
  }
}

// ------- fused gate+up GEMM, BK=64 [r9/r10-proven: ~70us, MfmaUtil 43%] ----
__global__ __launch_bounds__(256, 2) void gemm_gu(
    const u16* __restrict__ A, const u16* __restrict__ BgT,
    const u16* __restrict__ BuT,
    const float* __restrict__ bg, const float* __restrict__ bu,
    u16* __restrict__ H, int M, int N, int K)
{
  __shared__ __attribute__((aligned(16))) u16 As[128 * 64];
  __shared__ __attribute__((aligned(16))) u16 Gs[128 * 64];
  __shared__ __attribute__((aligned(16))) u16 Us[128 * 64];
  int tid = threadIdx.x;
  int m0 = blockIdx.y * 128, n0 = blockIdx.x * 128;
  int wave = tid >> 6, lane = tid & 63;
  int wm = (wave >> 1) * 64, wn = (wave & 1) * 64;
  int quad = lane >> 4, r16 = lane & 15;
  int s7 = r16 & 7;

  int srow = lane >> 3;
  int scol = ((lane & 7) ^ srow) * 8;
  const u16* aG = A   + (size_t)(m0 + wave * 32 + srow) * K + scol;
  const u16* gG = BgT + (size_t)(n0 + wave * 32 + srow) * K + scol;
  const u16* uG = BuT + (size_t)(n0 + wave * 32 + srow) * K + scol;

  f32x4 ag[4][4] = {}, au[4][4] = {};

  for (int k0 = 0; k0 < K; k0 += 64) {
#pragma unroll
    for (int idx = 0; idx < 4; ++idx) {
      size_t go = (size_t)idx * 8 * K + k0;
      int lo = wave * 2048 + idx * 512;
      GLOAD_LDS16(aG + go, As + lo);
      GLOAD_LDS16(gG + go, Gs + lo);
      GLOAD_LDS16(uG + go, Us + lo);
    }
    __syncthreads();
#pragma unroll
    for (int kk = 0; kk < 2; ++kk) {
      short8 af[4], bfr[4];
#pragma unroll
      for (int i = 0; i < 4; ++i)
        af[i] = *(const short8*)(&As[(wm + i * 16 + r16) * 64
                                     + (((kk << 2) + quad) ^ s7) * 8]);
#pragma unroll
      for (int j = 0; j < 4; ++j)
        bfr[j] = *(const short8*)(&Gs[(wn + j * 16 + r16) * 64
                                      + (((kk << 2) + quad) ^ s7) * 8]);
#pragma unroll
      for (int i = 0; i < 4; ++i)
#pragma unroll
        for (int j = 0; j < 4; ++j)
          ag[i][j] = __builtin_amdgcn_mfma_f32_16x16x32_bf16(af[i], bfr[j], ag[i][j], 0, 0, 0);
#pragma unroll
      for (int j = 0; j < 4; ++j)
        bfr[j] = *(const short8*)(&Us[(wn + j * 16 + r16) * 64
                                      + (((kk << 2) + quad) ^ s7) * 8]);
#pragma unroll
      for (int i = 0; i < 4; ++i)
#pragma unroll
        for (int j = 0; j < 4; ++j)
          au[i][j] = __builtin_amdgcn_mfma_f32_16x16x32_bf16(af[i], bfr[j], au[i][j], 0, 0, 0);
    }
    __syncthreads();
  }

#pragma unroll
  for (int i = 0; i < 4; ++i) {
    int row = m0 + wm + i * 16 + quad * 4;
#pragma unroll
    for (int j = 0; j < 4; ++j) {
      int col = n0 + wn + j * 16 + r16;
      float bgv = bg[col], buv = bu[col];
#pragma unroll
      for (int r = 0; r < 4; ++r) {
        float g = ag[i][j][r] + bgv;
        float u = au[i][j][r] + buv;
        float h = (g / (1.f + __expf(-g))) * u;
        H[(size_t)(row + r) * N + col] = f2b(h);
      }
    }
  }
}

// -------- split-K down-GEMM, BK=128 + FULL row&7 swizzle, XCD-aware [T1] ---
// r12: r11's BK=128 regression was the swizzle (XOR only (row&3)<<2 -> 2
// distinct blocks mod 8 -> 8-way conflict, counter-confirmed 6.29M). Fix:
// XOR by full row&7 = ((idx&1)<<2)|r4, folding the missing bit into the
// per-chunk SOURCE pointer (bits disjoint: r4 in 0..3, (idx&1)<<2 = bit 2).
// Read XOR = r16&7 -> 8-way spread mod 8 -> 2 lanes/bank (free, m136).
// LDS 64KB -> still 2 blocks/CU (grid 512 = 2/CU): drain overlap preserved.
// K-steps 32 -> 16 at constant per-step drain cost [r8/r9 drain model].
__global__ __launch_bounds__(256) void gemm_dsk(
    const u16* __restrict__ A, const u16* __restrict__ BT,
    float* __restrict__ P, int M, int N, int K, int Kslice, int mOff)
{
  __shared__ __attribute__((aligned(16))) u16 As[128 * 128];   // 32 KB
  __shared__ __attribute__((aligned(16))) u16 Bs[128 * 128];   // 32 KB
  int tid = threadIdx.x;

  int lid = blockIdx.x + blockIdx.y * gridDim.x +
            blockIdx.z * gridDim.x * gridDim.y;
  int G = gridDim.y * gridDim.z;          // (m,z) groups; n = gridDim.x = 8
  int n_blk, m_blk, z_blk;
  if ((G & 7) == 0) {
    int x = lid & 7, s = lid >> 3;        // XCD, per-XCD slot
    int gid = x * (G >> 3) + (s >> 3);    // group handled by this XCD
    n_blk = s & 7;
    m_blk = gid % gridDim.y;
    z_blk = gid / gridDim.y;
  } else {
    n_blk = blockIdx.x; m_blk = blockIdx.y; z_blk = blockIdx.z;
  }

  int m0 = m_blk * 128, n0 = n_blk * 128;
  int kb = z_blk * Kslice, ke = kb + Kslice;
  int wave = tid >> 6, lane = tid & 63;
  int wm = (wave >> 1) * 64, wn = (wave & 1) * 64;
  int quad = lane >> 4, r16 = lane & 15;
  int r4 = lane >> 4;                     // stage row-in-chunk (0..3)
  int c  = lane & 15;                     // stage 16B-block (0..15)

  const u16* aBase = A  + (size_t)(m0 + wave * 32 + r4) * K;
  const u16* bBase = BT + (size_t)(n0 + wave * 32 + r4) * K;

  f32x4 acc[4][4] = {};

  for (int k0 = kb; k0 < ke; k0 += 128) {
#pragma unroll
    for (int idx = 0; idx < 8; ++idx) {
      int sc = (c ^ r4 ^ ((idx & 1) << 2)) * 8;   // source col ^ (row&7)
      size_t go = (size_t)idx * 4 * K + k0 + sc;
      int lo = (wave * 32 + idx * 4) * 128;
      GLOAD_LDS16(aBase + go, As + lo);
      GLOAD_LDS16(bBase + go, Bs + lo);
    }
    __syncthreads();
#pragma unroll
    for (int kk = 0; kk < 4; ++kk) {
      int cb = (((kk << 2) + quad) ^ (r16 & 7)) * 8;
      short8 af[4], bfr[4];
#pragma unroll
      for (int i = 0; i < 4; ++i)
        af[i] = *(const short8*)(&As[(wm + i * 16 + r16) * 128 + cb]);
#pragma unroll
      for (int j = 0; j < 4; ++j)
        bfr[j] = *(const short8*)(&Bs[(wn + j * 16 + r16) * 128 + cb]);
#pragma unroll
      for (int i = 0; i < 4; ++i)
#pragma unroll
        for (int j = 0; j < 4; ++j)
          acc[i][j] = __builtin_amdgcn_mfma_f32_16x16x32_bf16(af[i], bfr[j], acc[i][j], 0, 0, 0);
    }
    __syncthreads();
  }

  float* Pz = P + (size_t)z_blk * 4194304;   // 4096*1024 per slice
#pragma unroll
  for (int i = 0; i < 4; ++i) {
    int row = mOff + m0 + wm + i * 16 + quad * 4;
#pragma unroll
    for (int j = 0; j < 4; ++j) {
      int col = n0 + wn + j * 16 + r16;
#pragma unroll
      for (int r = 0; r < 4; ++r)
        Pz[(size_t)(row + r) * N + col] = acc[i][j][r];
    }
  }
}

// ------- fused reduce: out = sum_s P[s] + es + bd (N = 1024) ---------------
__global__ __launch_bounds__(256) void reduce_k(const float* __restrict__ part,
                                                int S,
                                                const float* __restrict__ es,
                                                const float* __restrict__ bd,
                                                float* __restrict__ out) {
  int t = blockIdx.x, c0 = threadIdx.x * 4;
  size_t off = (size_t)t * 1024 + c0;
  f32x4 a = *(const f32x4*)(es + off);
  for (int s = 0; s < S; ++s) {
    f32x4 p = *(const f32x4*)(part + (size_t)s * 4194304 + off);
#pragma unroll
    for (int c = 0; c < 4; ++c) a[c] += p[c];
  }
  f32x4 b = *(const f32x4*)(bd + c0);
  f32x4 o;
#pragma unroll
  for (int c = 0; c < 4; ++c) o[c] = a[c] + b[c];
  *(f32x4*)(out + off) = o;
}

// ======== bitonic top-8-of-64 network helpers (values spread 1/lane) =======
template<int NP>
__device__ __forceinline__ void sort8_desc(float (&v)[NP], int (&ii)[NP], int j) {
#pragma unroll
  for (int k = 2; k <= 8; k <<= 1) {
#pragma unroll
    for (int s = k >> 1; s > 0; s >>= 1) {
      bool desc  = (j & k) == 0;
      bool lower = (j & s) == 0;
#pragma unroll
      for (int p = 0; p < NP; ++p) {
        float vp = __shfl_xor(v[p], s);
        int   ip = __shfl_xor(ii[p], s);
        bool mf = (v[p] > vp) || (v[p] == vp && ii[p] < ip);
        bool keep = (desc == lower) ? mf : !mf;
        if (!keep) { v[p] = vp; ii[p] = ip; }
      }
    }
  }
}

template<int NP>
__device__ __forceinline__ void merge_top8(float (&v)[NP], int (&ii)[NP], int j) {
#pragma unroll
  for (int r = 0; r < 3; ++r) {
    int mask = (8 << r) | 7;     // partner group, mirrored position
#pragma unroll
    for (int p = 0; p < NP; ++p) {
      float vp = __shfl_xor(v[p], mask);
      int   ip = __shfl_xor(ii[p], mask);
      bool mf = (v[p] > vp) || (v[p] == vp && ii[p] < ip);
      if (!mf) { v[p] = vp; ii[p] = ip; }   // elementwise max -> bitonic seq
    }
#pragma unroll
    for (int s = 4; s > 0; s >>= 1) {       // bitonic merge, descending
      bool lower = (j & s) == 0;
#pragma unroll
      for (int p = 0; p < NP; ++p) {
        float vq = __shfl_xor(v[p], s);
        int   iq = __shfl_xor(ii[p], s);
        bool mf = (v[p] > vq) || (v[p] == vq && ii[p] < iq);
        bool keep = lower ? mf : !mf;
        if (!keep) { v[p] = vq; ii[p] = iq; }
      }
    }
  }
}

// ---------------- product-key retrieval (bitonic top-k, in-register) -------
__global__ __launch_bounds__(256) void retrieve_k(
    const u16*  __restrict__ q,      // bf16 [4096][512] = [t][p(2)][h(4)][n(64)]
    const float* __restrict__ keysT, // fp32 [4][2][64][64] = [h][p][n][k]
    int* __restrict__ idx_out,       // [4096][4][8]
    float* __restrict__ p_out)       // [4096][4][8]
{
  int t = blockIdx.x;
  int w = threadIdx.x >> 6, lane = threadIdx.x & 63;
  int j = lane & 7;

  float v[2]; int ii[2];
#pragma unroll
  for (int p = 0; p < 2; ++p) {
    const u16*   qp = q + (size_t)t * 512 + p * 256 + w * 64;   // broadcast
    const float* kp = keysT + ((size_t)(w * 2 + p) * 64) * 64 + lane;
    float s0 = 0.f, s1 = 0.f, s2 = 0.f, s3 = 0.f;   // 4-way fma ILP
#pragma unroll
    for (int n = 0; n < 64; n += 8) {
      B8 qv; qv.v = *(const short8*)(qp + n);
      s0 += b2f(qv.u[0]) * kp[(size_t)(n + 0) * 64];
      s1 += b2f(qv.u[1]) * kp[(size_t)(n + 1) * 64];
      s2 += b2f(qv.u[2]) * kp[(size_t)(n + 2) * 64];
      s3 += b2f(qv.u[3]) * kp[(size_t)(n + 3) * 64];
      s0 += b2f(qv.u[4]) * kp[(size_t)(n + 4) * 64];
      s1 += b2f(qv.u[5]) * kp[(size_t)(n + 5) * 64];
      s2 += b2f(qv.u[6]) * kp[(size_t)(n + 6) * 64];
      s3 += b2f(qv.u[7]) * kp[(size_t)(n + 7) * 64];
    }
    v[p] = (s0 + s1) + (s2 + s3); ii[p] = lane;
  }

  // phase 1: per-half top-8 of 64 (two interleaved networks)
  sort8_desc<2>(v, ii, j);
  merge_top8<2>(v, ii, j);

  // phase 2: 64 combo sums; groups pre-sorted (sy sorted), merge only
  float v2[1] = { __shfl(v[0], lane >> 3) + __shfl(v[1], lane & 7) };
  int  pos[1] = { lane };                   // combo position = tie-break key
  merge_top8<1>(v2, pos, j);

  int ex = __shfl(ii[0], pos[0] >> 3);
  int ey = __shfl(ii[1], pos[0] & 7);

  float m = __shfl(v2[0], 0);
  float e = __expf(v2[0] - m);
  float sum = e;
#pragma unroll
  for (int s = 4; s > 0; s >>= 1) sum += __shfl_xor(sum, s);

  if (lane < 8) {
    int o = (t * 4 + w) * 8 + lane;
    p_out[o]   = e / sum;
    idx_out[o] = ex * 64 + ey;
  }
}

// ---------- expert gather + weighted sum: 8 waves, 4 experts/wave ----------
__global__ __launch_bounds__(512) void expert_k(
    const u16* __restrict__ xb, const u16* __restrict__ downb,
    const u16* __restrict__ upb,
    const int* __restrict__ idx, const float* __restrict__ probs,
    float* __restrict__ es)     // [4096][1024] fp32
{
  __shared__ float acc_s[8][1024];   // 32 KB
  int t = blockIdx.x;
  int w = threadIdx.x >> 6, lane = threadIdx.x & 63;
  const size_t tb = (size_t)t * 1024;
  const int lo = lane * 8;

  B8 xv0, xv1;
  xv0.v = *(const short8*)(xb + tb + lo);
  xv1.v = *(const short8*)(xb + tb + 512 + lo);
  float xf[16];
#pragma unroll
  for (int c = 0; c < 8; ++c) { xf[c] = b2f(xv0.u[c]); xf[8 + c] = b2f(xv1.u[c]); }

  float a[16] = {};
#pragma unroll
  for (int e4 = 0; e4 < 4; ++e4) {
    int e = w * 4 + e4;
    int id = idx[t * 32 + e];
    const u16* dp = downb + (size_t)id * 1024;
    B8 d0, d1;
    d0.v = *(const short8*)(dp + lo);
    d1.v = *(const short8*)(dp + 512 + lo);
    float part = 0.f;
#pragma unroll
    for (int c = 0; c < 8; ++c)
      part += xf[c] * b2f(d0.u[c]) + xf[8 + c] * b2f(d1.u[c]);
#pragma unroll
    for (int off = 32; off; off >>= 1) part += __shfl_xor(part, off);
    float gate = (part / (1.f + __expf(-part))) * probs[t * 32 + e];
    const u16* upp = upb + (size_t)id * 1024;
    B8 u0, u1;
    u0.v = *(const short8*)(upp + lo);
    u1.v = *(const short8*)(upp + 512 + lo);
#pragma unroll
    for (int c = 0; c < 8; ++c) {
      a[c]     += gate * b2f(u0.u[c]);
      a[8 + c] += gate * b2f(u1.u[c]);
    }
  }
#pragma unroll
  for (int c = 0; c < 8; ++c) {
    acc_s[w][lo + c]       = a[c];
    acc_s[w][512 + lo + c] = a[8 + c];
  }
  __syncthreads();
  int d0i = threadIdx.x * 2;
  float o0 = 0.f, o1 = 0.f;
#pragma unroll
  for (int ww = 0; ww < 8; ++ww) {
    o0 += acc_s[ww][d0i];
    o1 += acc_s[ww][d0i + 1];
  }
  f32x2 o; o[0] = o0; o[1] = o1;
  *(f32x2*)(es + tb + d0i) = o;
}

extern "C" void kernel_launch(void* const* d_in, const int* in_sizes, int n_in,
                              void* d_out, int out_size, void* d_ws, size_t ws_size,
                              hipStream_t stream)
{
  const float* x    = (const float*)d_in[0];
  const float* Wg   = (const float*)d_in[1];
  const float* bg   = (const float*)d_in[2];
  const float* Wu   = (const float*)d_in[3];
  const float* bu   = (const float*)d_in[4];
  const float* Wd   = (const float*)d_in[5];
  const float* bd   = (const float*)d_in[6];
  const float* Wq   = (const float*)d_in[7];
  const float* keys = (const float*)d_in[8];
  const float* down = (const float*)d_in[9];
  const float* up   = (const float*)d_in[10];
  float* out = (float*)d_out;

  // --- workspace layout ---
  const size_t MB = 1048576;
  char* ws = (char*)d_ws;
  u16*   xb    = (u16*)(ws);                 // 8 MB  bf16 x [4096][1024]
  u16*   WgT   = (u16*)(ws + 8  * MB);       // 8 MB  bf16 [4096][1024]
  u16*   WuT   = (u16*)(ws + 16 * MB);       // 8 MB
  u16*   WdT   = (u16*)(ws + 24 * MB);       // 8 MB  bf16 [1024][4096]
  float* es    = (float*)(ws + 32 * MB);     // 16 MB fp32 [4096][1024]
  u16*   WqT   = (u16*)(ws + 32 * MB);       // 1 MB, aliases es head (dead first)
  u16*   qb    = (u16*)(ws + 34 * MB);       // 4 MB, aliases es (dead first)
  float* keysT = (float*)(ws + 47 * MB);     // 128 KB, aliases es tail (dead first)
  int*   idxb  = (int*)(ws + 48 * MB);       // 512 KB
  float* prb   = (float*)(ws + 48 * MB + 512 * 1024);
  u16*   downb = (u16*)(ws + 49 * MB);       // 8 MB bf16 [4096][1024]
  u16*   upb   = (u16*)(ws + 57 * MB);       // 8 MB

  // split-K partials for down-GEMM: S x 16 MB fp32 [4096][1024], then gb
  int S = 2;
  while (S > 1 && 65 * MB + (size_t)S * 16 * MB + 1 * MB > ws_size) S >>= 1;
  float* part = (float*)(ws + 65 * MB);
  size_t gboff = 65 * MB + (size_t)S * 16 * MB;
  u16*   gb    = (u16*)(ws + gboff);         // chunk_rows x 4096 bf16 (h1)

  size_t avail = ws_size > gboff ? ws_size - gboff : 0;
  int rows = 4096;                           // rows per MLP chunk
  while (rows > 128 && (size_t)rows * 4096 * 2 > avail) rows >>= 1;
  int Ksl = 4096 / S;

  // conversions (fp32 -> bf16; weights fused with transpose)
  cvt3<<<12288, 256, 0, stream>>>(x, down, up, xb, downb, upb);
  convt_w<<<dim3(16, 16),  256, 0, stream>>>(Wq, WqT, nullptr, nullptr, 1024, 512);
  convt_w<<<dim3(16, 128, 2), 256, 0, stream>>>(Wg, WgT, Wu, WuT, 1024, 4096);
  convt_w<<<dim3(64, 32),  256, 0, stream>>>(Wd, WdT, nullptr, nullptr, 4096, 1024);
  convt_keys<<<dim3(4, 2), 256, 0, stream>>>(keys, keysT);

  // retrieval chain: q = x@Wq -> topk experts -> es
  gemm_bf16<<<dim3(4, 32), 256, 0, stream>>>(xb, WqT, nullptr,
                                             qb, 4096, 512, 1024);
  retrieve_k<<<4096, 256, 0, stream>>>(qb, keysT, idxb, prb);
  expert_k<<<4096, 512, 0, stream>>>(xb, downb, upb, idxb, prb, es);

  // MLP chain: h1 = silu(x@Wg+bg)*(x@Wu+bu); P[s] = h1@Wd (split-K stores)
  for (int m0c = 0; m0c < 4096; m0c += rows) {
    int gy = rows / 128;
    gemm_gu<<<dim3(32, gy), 256, 0, stream>>>(xb + (size_t)m0c * 1024, WgT, WuT,
                                              bg, bu, gb, rows, 4096, 1024);
    gemm_dsk<<<dim3(8, gy, S), 256, 0, stream>>>(gb, WdT, part,
                                                 rows, 1024, 4096, Ksl, m0c);
  }
  // fused epilogue: out = sum_s P[s] + es + bd
  reduce_k<<<4096, 256, 0, stream>>>(part, S, es, bd, out);
}